// Round 13
// baseline (161.509 us; speedup 1.0000x reference)
//
#include <hip/hip_runtime.h>

#define D 128
#define SCAN_BLK 256

typedef short  bf16x8 __attribute__((ext_vector_type(8)));
typedef float  f32x4  __attribute__((ext_vector_type(4)));

// round-to-nearest-even float -> bf16 bits
static __device__ __forceinline__ unsigned short f2bf(float f) {
    unsigned u = __float_as_uint(f);
    u += 0x7FFFu + ((u >> 16) & 1u);
    return (unsigned short)(u >> 16);
}
static __device__ __forceinline__ float bf2f_lo(unsigned u) {
    return __uint_as_float((u & 0xFFFFu) << 16);
}
static __device__ __forceinline__ float bf2f_hi(unsigned u) {
    return __uint_as_float(u & 0xFFFF0000u);
}

// --------------------------------- fused: class-partitioned hist + convert_W
// Edge i's class = (i>>8)&7 = chunk index mod 8. Hist block bid processes
// chunk bid, so cls == bid&7 == this block's XCD (round-robin dispatch):
// counts8 lines for class k are only touched by XCD k -> no L2 line bouncing.
__global__ __launch_bounds__(256) void fused_pre(
    const int* __restrict__ rows, int* __restrict__ counts8,
    int n_edges, int n_nodes,
    const float* __restrict__ W, unsigned short* __restrict__ Wb, int histBlocks) {
    int bid = blockIdx.x;
    if (bid < histBlocks) {
        int i = bid * 256 + threadIdx.x;
        if (i < n_edges) {
            int cls = (i >> 8) & 7;
            atomicAdd(&counts8[cls * n_nodes + rows[i]], 1);
        }
    } else {
        int i = (bid - histBlocks) * 256 + threadIdx.x;
        if (i < D * D) Wb[i] = f2bf(W[i]);
    }
}

// ---------------------------------------------------------------- scan chain
// over 8*n_nodes class-major counts -> offs8[0..8N], cursor8 copy.
__global__ __launch_bounds__(SCAN_BLK) void scan_local(
    const int* __restrict__ counts, int* __restrict__ offs,
    int* __restrict__ blockSums, int n) {
    __shared__ int sh[SCAN_BLK];
    const int t = threadIdx.x;
    const int i = blockIdx.x * SCAN_BLK + t;
    int v = (i < n) ? counts[i] : 0;
    sh[t] = v;
    __syncthreads();
    for (int off = 1; off < SCAN_BLK; off <<= 1) {
        int add = (t >= off) ? sh[t - off] : 0;
        __syncthreads();
        sh[t] += add;
        __syncthreads();
    }
    if (i < n) offs[i] = sh[t] - v;
    if (t == SCAN_BLK - 1) blockSums[blockIdx.x] = sh[SCAN_BLK - 1];
}

// single block, 2 elements/thread: nb <= 2048
__global__ __launch_bounds__(1024) void scan_blocks2(
    int* __restrict__ blockSums, int* __restrict__ total, int nb) {
    __shared__ int sh[1024];
    const int t = threadIdx.x;
    int c0 = (t * 2     < nb) ? blockSums[t * 2]     : 0;
    int c1 = (t * 2 + 1 < nb) ? blockSums[t * 2 + 1] : 0;
    sh[t] = c0 + c1;
    __syncthreads();
    for (int off = 1; off < 1024; off <<= 1) {
        int add = (t >= off) ? sh[t - off] : 0;
        __syncthreads();
        sh[t] += add;
        __syncthreads();
    }
    int base = sh[t] - (c0 + c1);
    if (t * 2 < nb)     blockSums[t * 2]     = base;
    if (t * 2 + 1 < nb) blockSums[t * 2 + 1] = base + c0;
    if (t == 1023) *total = sh[1023];
}

__global__ __launch_bounds__(SCAN_BLK) void scan_add(
    int* __restrict__ offs, int* __restrict__ cursor,
    const int* __restrict__ blockSums, int n) {
    const int i = blockIdx.x * SCAN_BLK + threadIdx.x;
    if (i < n) {
        int o = offs[i] + blockSums[blockIdx.x];
        offs[i]   = o;
        cursor[i] = o;
    }
}

// ------------------------------------------------ fused: permute + MFMA GEMM
// r5<2: gemm. r5>=2: permute, but each permute block handles ONLY chunks of
// class k = bid&7 (its own XCD, round-robin assumption) -> each class's
// cursor8/evec region is written by a single XCD's L2 -> lines absorb all
// their records before writeback (R10 lesson: cross-XCD writers make every
// 8B record cost a 64B line migration).
__global__ __launch_bounds__(256) void fused_main(
    const int* __restrict__ rows, const int* __restrict__ cols,
    const float* __restrict__ vals, int* __restrict__ cursor8,
    int2* __restrict__ evec, int n_edges, int n_nodes,
    int nChunks, int QperClass,
    const float* __restrict__ x, const unsigned short* __restrict__ Wb,
    const float* __restrict__ b, unsigned short* __restrict__ hb, int n_rows) {
    const int bid = blockIdx.x;
    const int r5  = bid % 5;

    if (r5 >= 2) {
        const int k   = bid & 7;
        const int S   = bid / 40;         // supergroup of 40 (lcm(5,8))
        const int pos = bid % 40;
        int r = 0;                        // rank among same-class permute bids in group
        for (int p = 0; p < pos; ++p)
            if ((p % 5) >= 2 && (p & 7) == k) ++r;
        const int q = S * 3 + r;          // 3 same-class permute blocks per 40
        for (int m = q; ; m += QperClass) {
            int c = k + 8 * m;            // chunk index, c%8==k
            if (c >= nChunks) break;
            int i = c * 256 + threadIdx.x;
            if (i < n_edges) {
                int rr  = rows[i];
                int pp  = atomicAdd(&cursor8[k * n_nodes + rr], 1);
                evec[pp] = make_int2(cols[i], __float_as_int(vals[i]));
            }
        }
        return;
    }

    // ---- gemm slot: h[m][o] = sum_k x[m][k]*W[o][k] + b[o] -> bf16
    const int gb   = (bid / 5) * 2 + r5;
    const int lane = threadIdx.x & 63;
    const int wv   = threadIdx.x >> 6;
    const int row0 = gb * 64 + wv * 16;
    if (row0 >= n_rows) return;           // no __syncthreads in this path
    const int m  = lane & 15;
    const int kg = lane >> 4;             // 0..3

    int arow = row0 + m;
    if (arow >= n_rows) arow = n_rows - 1;
    const float* xr = x + (size_t)arow * D + kg * 8;

    f32x4 acc[8];
#pragma unroll
    for (int n = 0; n < 8; ++n) acc[n] = (f32x4){0.f, 0.f, 0.f, 0.f};

#pragma unroll
    for (int ks = 0; ks < 4; ++ks) {
        float4 f0 = *(const float4*)(xr + ks * 32);
        float4 f1 = *(const float4*)(xr + ks * 32 + 4);
        bf16x8 a;
        a[0] = (short)f2bf(f0.x); a[1] = (short)f2bf(f0.y);
        a[2] = (short)f2bf(f0.z); a[3] = (short)f2bf(f0.w);
        a[4] = (short)f2bf(f1.x); a[5] = (short)f2bf(f1.y);
        a[6] = (short)f2bf(f1.z); a[7] = (short)f2bf(f1.w);
#pragma unroll
        for (int n = 0; n < 8; ++n) {
            bf16x8 bf = *(const bf16x8*)&Wb[(size_t)(n * 16 + m) * D + ks * 32 + kg * 8];
            acc[n] = __builtin_amdgcn_mfma_f32_16x16x32_bf16(a, bf, acc[n], 0, 0, 0);
        }
    }

#pragma unroll
    for (int n = 0; n < 8; ++n) {
        int col = n * 16 + m;
        float bc = b[col];
#pragma unroll
        for (int j = 0; j < 4; ++j) {
            int rr = row0 + kg * 4 + j;
            if (rr < n_rows) hb[(size_t)rr * D + col] = f2bf(acc[n][j] + bc);
        }
    }
}

// ---------------------------------------------------------------- aggregate
// Two nodes per wave (half-wave = 32 lanes; lane owns 4 cols = 8 B of row).
// Per node: 8 class regions [offs8[c*N+node], offs8[c*N+node+1]).
// Each round takes record rd of EVERY class (masked, clamped) -> 8
// independent evec loads + 8 gathers per round, rounds = max class count.
__global__ __launch_bounds__(256, 4) void aggregate(
    const int* __restrict__ offs8, const int2* __restrict__ evec,
    const unsigned short* __restrict__ hb, float* __restrict__ out,
    int n_nodes, int n_edges) {
    const int lane = threadIdx.x & 63;
    const int hl   = lane >> 5;
    const int node = (blockIdx.x * 4 + (threadIdx.x >> 6)) * 2 + hl;
    const int c0   = (lane & 31) * 4;

    int s[8], cnt[8];
    int rounds = 0;
    if (node < n_nodes) {
#pragma unroll
        for (int c = 0; c < 8; ++c) {
            int a  = offs8[c * n_nodes + node];
            int bd = offs8[c * n_nodes + node + 1];
            s[c]   = a;
            cnt[c] = bd - a;
            rounds = max(rounds, cnt[c]);
        }
    } else {
#pragma unroll
        for (int c = 0; c < 8; ++c) { s[c] = 0; cnt[c] = 0; }
    }

    float4 acc = make_float4(0.f, 0.f, 0.f, 0.f);
    const int emax = n_edges - 1;

    for (int rd = 0; rd < rounds; ++rd) {
        int2  rec[8];
#pragma unroll
        for (int c = 0; c < 8; ++c) {
            int idx = s[c] + min(rd, max(cnt[c] - 1, 0));
            rec[c] = evec[min(idx, emax)];
        }
        uint2 u[8];
#pragma unroll
        for (int c = 0; c < 8; ++c)
            u[c] = *(const uint2*)&hb[(size_t)rec[c].x * D + c0];
#pragma unroll
        for (int c = 0; c < 8; ++c) {
            float v = (rd < cnt[c]) ? __int_as_float(rec[c].y) : 0.f;
            acc.x += v * bf2f_lo(u[c].x); acc.y += v * bf2f_hi(u[c].x);
            acc.z += v * bf2f_lo(u[c].y); acc.w += v * bf2f_hi(u[c].y);
        }
    }

    if (node < n_nodes)
        *(float4*)&out[(size_t)node * D + c0] = acc;
}

// ---------------------------------------------------------------- fallback
__global__ void convert_W(const float* __restrict__ W, unsigned short* __restrict__ Wb) {
    int i = blockIdx.x * blockDim.x + threadIdx.x;
    if (i < D * D) Wb[i] = f2bf(W[i]);
}

__global__ __launch_bounds__(256) void gemm_mfma(
    const float* __restrict__ x, const unsigned short* __restrict__ Wb,
    const float* __restrict__ b, unsigned short* __restrict__ hb, int n_rows) {
    const int lane = threadIdx.x & 63;
    const int wv   = threadIdx.x >> 6;
    const int row0 = blockIdx.x * 64 + wv * 16;
    if (row0 >= n_rows) return;
    const int m  = lane & 15;
    const int kg = lane >> 4;
    int arow = row0 + m;
    if (arow >= n_rows) arow = n_rows - 1;
    const float* xr = x + (size_t)arow * D + kg * 8;
    f32x4 acc[8];
#pragma unroll
    for (int n = 0; n < 8; ++n) acc[n] = (f32x4){0.f, 0.f, 0.f, 0.f};
#pragma unroll
    for (int ks = 0; ks < 4; ++ks) {
        float4 f0 = *(const float4*)(xr + ks * 32);
        float4 f1 = *(const float4*)(xr + ks * 32 + 4);
        bf16x8 a;
        a[0] = (short)f2bf(f0.x); a[1] = (short)f2bf(f0.y);
        a[2] = (short)f2bf(f0.z); a[3] = (short)f2bf(f0.w);
        a[4] = (short)f2bf(f1.x); a[5] = (short)f2bf(f1.y);
        a[6] = (short)f2bf(f1.z); a[7] = (short)f2bf(f1.w);
#pragma unroll
        for (int n = 0; n < 8; ++n) {
            bf16x8 bf = *(const bf16x8*)&Wb[(size_t)(n * 16 + m) * D + ks * 32 + kg * 8];
            acc[n] = __builtin_amdgcn_mfma_f32_16x16x32_bf16(a, bf, acc[n], 0, 0, 0);
        }
    }
#pragma unroll
    for (int n = 0; n < 8; ++n) {
        int col = n * 16 + m;
        float bc = b[col];
#pragma unroll
        for (int j = 0; j < 4; ++j) {
            int r = row0 + kg * 4 + j;
            if (r < n_rows) hb[(size_t)r * D + col] = f2bf(acc[n][j] + bc);
        }
    }
}

__global__ __launch_bounds__(256) void scatter_add(
    const int* __restrict__ rows, const int* __restrict__ cols,
    const float* __restrict__ vals, const unsigned short* __restrict__ hb,
    float* __restrict__ out, int n_edges) {
    long long gid = (long long)blockIdx.x * blockDim.x + threadIdx.x;
    int e  = (int)(gid >> 5);
    if (e >= n_edges) return;
    int d4 = ((int)gid & 31) * 4;
    int   r = rows[e];
    int   c = cols[e];
    float v = vals[e];
    const unsigned short* hp = &hb[(size_t)c * D + d4];
    unsigned u0 = *(const unsigned*)(hp + 0);
    unsigned u1 = *(const unsigned*)(hp + 2);
    float* op = &out[(size_t)r * D + d4];
    atomicAdd(op + 0, v * bf2f_lo(u0));
    atomicAdd(op + 1, v * bf2f_hi(u0));
    atomicAdd(op + 2, v * bf2f_lo(u1));
    atomicAdd(op + 3, v * bf2f_hi(u1));
}

// ---------------------------------------------------------------- launch
static inline size_t align16(size_t x) { return (x + 15) & ~(size_t)15; }

extern "C" void kernel_launch(void* const* d_in, const int* in_sizes, int n_in,
                              void* d_out, int out_size, void* d_ws, size_t ws_size,
                              hipStream_t stream) {
    const float* x    = (const float*)d_in[0];
    const int*   rows = (const int*)  d_in[1];
    const int*   cols = (const int*)  d_in[2];
    const float* vals = (const float*)d_in[3];
    const float* W    = (const float*)d_in[4];
    const float* b    = (const float*)d_in[5];
    float*       out  = (float*)d_out;

    const int n_nodes = in_sizes[0] / D;   // 50000
    const int n_edges = in_sizes[1];       // 800000
    const int histBlocks = (n_edges + 255) / 256;          // 3125 (= nChunks)
    const int convBlocks = (D * D + 255) / 256;            // 64
    const int gemmBlocks = (n_nodes + 63) / 64;            // 782
    const int nSuper     = (gemmBlocks + 15) / 16;         // 49 supergroups of 40
    const int mainBlocks = nSuper * 40;                    // 1960
    const int QperClass  = nSuper * 3;                     // 147
    const int n8         = 8 * n_nodes;                    // 400000
    const int nScanBlocks = (n8 + SCAN_BLK - 1) / SCAN_BLK; // 1563
    const int aggBlocks  = (n_nodes + 7) / 8;

    // ---- workspace layout (16B-aligned regions)
    char*  base    = (char*)d_ws;
    size_t off     = 0;
    unsigned short* Wb = (unsigned short*)(base + off); off = align16(off + (size_t)D * D * 2);
    unsigned short* hb = (unsigned short*)(base + off); off = align16(off + (size_t)n_nodes * D * 2);
    int*   counts8 = (int*)  (base + off); off = align16(off + (size_t)n8 * 4);
    int*   offs8   = (int*)  (base + off); off = align16(off + ((size_t)n8 + 1) * 4);
    int*   cursor8 = (int*)  (base + off); off = align16(off + (size_t)n8 * 4);
    int*   bsums   = (int*)  (base + off); off = align16(off + (size_t)2048 * 4);
    int2*  evec    = (int2*) (base + off); off = align16(off + (size_t)n_edges * 8);
    const bool ok = (off <= ws_size) && (nScanBlocks <= 2048);

    if (ok) {
        hipMemsetAsync(counts8, 0, (size_t)n8 * 4, stream);
        fused_pre<<<histBlocks + convBlocks, 256, 0, stream>>>(
            rows, counts8, n_edges, n_nodes, W, Wb, histBlocks);
        scan_local<<<nScanBlocks, SCAN_BLK, 0, stream>>>(counts8, offs8, bsums, n8);
        scan_blocks2<<<1, 1024, 0, stream>>>(bsums, &offs8[n8], nScanBlocks);
        scan_add<<<nScanBlocks, SCAN_BLK, 0, stream>>>(offs8, cursor8, bsums, n8);
        fused_main<<<mainBlocks, 256, 0, stream>>>(
            rows, cols, vals, cursor8, evec, n_edges, n_nodes,
            histBlocks, QperClass, x, Wb, b, hb, n_nodes);
        aggregate<<<aggBlocks, 256, 0, stream>>>(
            offs8, evec, hb, out, n_nodes, n_edges);
    } else {
        convert_W<<<convBlocks, 256, 0, stream>>>(W, Wb);
        gemm_mfma<<<gemmBlocks, 256, 0, stream>>>(x, Wb, b, hb, n_nodes);
        hipMemsetAsync(d_out, 0, (size_t)n_nodes * D * sizeof(float), stream);
        long long scatter_threads = (long long)n_edges * 32;
        int scatter_blocks = (int)((scatter_threads + 255) / 256);
        scatter_add<<<scatter_blocks, 256, 0, stream>>>(rows, cols, vals, hb, out, n_edges);
    }
}